// Round 2
// baseline (3034.996 us; speedup 1.0000x reference)
//
#include <hip/hip_runtime.h>
#include <cstdint>

typedef __bf16 bf16;
typedef bf16 bf16x8 __attribute__((ext_vector_type(8)));
typedef bf16 bf16x4 __attribute__((ext_vector_type(4)));
typedef float f32x4 __attribute__((ext_vector_type(4)));

#define DEVI __device__ __forceinline__

// Direct global->LDS (width 16). LDS dest is wave-uniform base; HW adds lane*16.
DEVI void gload_lds16(const void* g, void* l) {
  typedef __attribute__((address_space(1))) void gas_t;
  typedef __attribute__((address_space(3))) void las_t;
  __builtin_amdgcn_global_load_lds((gas_t*)g, (las_t*)l, 16, 0, 0);
}

// ---------------------------------------------------------------------------
// Weight cast f32 -> bf16
// ---------------------------------------------------------------------------
__global__ void cast_w(const float* __restrict__ in, bf16* __restrict__ out, int n) {
  int i = (blockIdx.x * 256 + threadIdx.x) * 4;
  if (i >= n) return;
  f32x4 v = *(const f32x4*)(in + i);
  bf16x4 o;
#pragma unroll
  for (int j = 0; j < 4; j++) o[j] = (bf16)v[j];
  *(bf16x4*)(out + i) = o;
}

// ---------------------------------------------------------------------------
// LayerNorm (+ optional cyclic shift & window partition gather), f32 -> bf16
// One wave per 512-elem row; 8 elems/lane.
// Window-order row = b*4096 + w*64 + t reads shifted pixel ((wh*8+th+4)&63, (ww*8+tw+4)&63)
// ---------------------------------------------------------------------------
template<bool PERM>
__global__ __launch_bounds__(256, 4) void ln_bf16(
    const float* __restrict__ in, const float* __restrict__ gam,
    const float* __restrict__ bet, bf16* __restrict__ out)
{
  const int row = blockIdx.x * 4 + (threadIdx.x >> 6);
  const int lane = threadIdx.x & 63;
  size_t src;
  if constexpr (PERM) {
    const int rem = row & 4095, w = rem >> 6, t = rem & 63;
    const int r0 = ((w >> 3) * 8 + (t >> 3) + 4) & 63;
    const int c0 = ((w & 7) * 8 + (t & 7) + 4) & 63;
    src = ((size_t)(row >> 12) * 4096 + r0 * 64 + c0) * 512;
  } else {
    src = (size_t)row * 512;
  }
  const f32x4 v0 = *(const f32x4*)(in + src + lane * 8);
  const f32x4 v1 = *(const f32x4*)(in + src + lane * 8 + 4);
  float s  = v0[0] + v0[1] + v0[2] + v0[3] + v1[0] + v1[1] + v1[2] + v1[3];
  float sq = v0[0]*v0[0] + v0[1]*v0[1] + v0[2]*v0[2] + v0[3]*v0[3]
           + v1[0]*v1[0] + v1[1]*v1[1] + v1[2]*v1[2] + v1[3]*v1[3];
#pragma unroll
  for (int m = 1; m < 64; m <<= 1) { s += __shfl_xor(s, m, 64); sq += __shfl_xor(sq, m, 64); }
  const float mean = s * 0.001953125f;
  const float rstd = rsqrtf(sq * 0.001953125f - mean * mean + 1e-5f);
  const f32x4 g0 = *(const f32x4*)(gam + lane * 8), g1 = *(const f32x4*)(gam + lane * 8 + 4);
  const f32x4 b0 = *(const f32x4*)(bet + lane * 8), b1 = *(const f32x4*)(bet + lane * 8 + 4);
  bf16x8 o;
#pragma unroll
  for (int j = 0; j < 4; j++) o[j]     = (bf16)((v0[j] - mean) * rstd * g0[j] + b0[j]);
#pragma unroll
  for (int j = 0; j < 4; j++) o[4 + j] = (bf16)((v1[j] - mean) * rstd * g1[j] + b1[j]);
  *(bf16x8*)(out + (size_t)row * 512 + lane * 8) = o;
}

// ---------------------------------------------------------------------------
// bf16 GEMM: C[m,n] = sum_k A[m,k] * W[n,k]  (+ per-mode epilogue)
// 128x128 tile, BK=32, 4 waves (2x2), 16x16x32 MFMA, global_load_lds width 16.
// LDS layout is k-group-major: 16B unit u = kg*128 + row  -> conflict-free
// ds_read_b128 fragment reads (lanes 0..15 hit consecutive 16B units).
// ---------------------------------------------------------------------------
constexpr int M_QKV = 0, M_PROJ = 1, M_FC1 = 2, M_FC2 = 3;

template<int MODE>
__global__ __launch_bounds__(256, 2) void gemm_bt(
    const bf16* __restrict__ A, const bf16* __restrict__ W,
    const float* __restrict__ bias, void* __restrict__ Cout,
    const float* __restrict__ extra, int N, int K, int ldc)
{
  __shared__ bf16 sA[4096];
  __shared__ bf16 sB[4096];
  const int nN = N >> 7;
  const unsigned nwg = gridDim.x;
  // XCD-aware swizzle (all grids divisible by 8); bn-fast for A-panel L2 reuse
  const unsigned id = (blockIdx.x & 7) * (nwg >> 3) + (blockIdx.x >> 3);
  const int bn = id % nN;
  const int bm = id / nN;
  const int lane = threadIdx.x & 63;
  const int wave = threadIdx.x >> 6;
  const int wr = wave >> 1, wc = wave & 1;
  const size_t m0 = (size_t)bm * 128, n0 = (size_t)bn * 128;

  f32x4 acc[4][4] = {};

  for (int k0 = 0; k0 < K; k0 += 32) {
    __syncthreads();
#pragma unroll
    for (int c = wave; c < 8; c += 4) {
      const int u = c * 64 + lane;           // 16B unit index in tile
      const int rr = u & 127, kg = u >> 7;   // row, k-group
      gload_lds16(A + (m0 + rr) * K + k0 + kg * 8, (char*)sA + c * 1024);
      gload_lds16(W + (n0 + rr) * K + k0 + kg * 8, (char*)sB + c * 1024);
    }
    __syncthreads();
    bf16x8 af[4], bw[4];
#pragma unroll
    for (int i = 0; i < 4; i++) {
      af[i] = *(const bf16x8*)&sA[(lane >> 4) * 1024 + (wr * 64 + i * 16 + (lane & 15)) * 8];
      bw[i] = *(const bf16x8*)&sB[(lane >> 4) * 1024 + (wc * 64 + i * 16 + (lane & 15)) * 8];
    }
#pragma unroll
    for (int i = 0; i < 4; i++)
#pragma unroll
      for (int j = 0; j < 4; j++)
        acc[i][j] = __builtin_amdgcn_mfma_f32_16x16x32_bf16(af[i], bw[j], acc[i][j], 0, 0, 0);
  }

  // epilogue: C/D layout col=lane&15, row=(lane>>4)*4+r (m89-verified)
  const int colb = (int)n0 + wc * 64 + (lane & 15);
  const int rowb = (int)m0 + wr * 64 + ((lane >> 4) << 2);
#pragma unroll
  for (int j = 0; j < 4; j++) {
    const int col = colb + j * 16;
    const float bv = bias[col];
#pragma unroll
    for (int i = 0; i < 4; i++) {
#pragma unroll
      for (int r = 0; r < 4; r++) {
        const int row = rowb + i * 16 + r;
        float v = acc[i][j][r] + bv;
        if constexpr (MODE == M_QKV) {
          ((bf16*)Cout)[(size_t)row * ldc + col] = (bf16)v;
        } else if constexpr (MODE == M_FC1) {
          v = 0.5f * v * (1.0f + erff(v * 0.70710678118f));   // exact GELU
          ((bf16*)Cout)[(size_t)row * ldc + col] = (bf16)v;
        } else if constexpr (MODE == M_PROJ) {
          // window reverse + unshift + residual: x1[b,pix,col] = x[b,pix,col] + v
          const int rem = row & 4095, w = rem >> 6, t = rem & 63;
          const int r0 = ((w >> 3) * 8 + (t >> 3) + 4) & 63;
          const int c0 = ((w & 7) * 8 + (t & 7) + 4) & 63;
          const size_t idx = ((size_t)(row >> 12) * 4096 + r0 * 64 + c0) * 512 + col;
          ((float*)Cout)[idx] = extra[idx] + v;
        } else { // M_FC2: out = v + x1 (residual), f32
          const size_t idx = (size_t)row * 512 + col;
          ((float*)Cout)[idx] = extra[idx] + v;
        }
      }
    }
  }
}

// ---------------------------------------------------------------------------
// Windowed attention: one block per (window, head). 4 waves split the 64 q-rows.
// S = (Q*scale) K^T + rel-pos-bias + shift-mask (both computed inline), softmax,
// O = P V. P (per-wave 16x64) and V^T (32x64) staged in XOR-swizzled LDS.
// ---------------------------------------------------------------------------
DEVI int zone3(int r) { return r < 56 ? 0 : (r < 60 ? 1 : 2); }

__global__ __launch_bounds__(256, 2) void attn_win(
    const bf16* __restrict__ qkv, const float* __restrict__ rpb, bf16* __restrict__ out)
{
  __shared__ bf16 sP[4][1024];   // per-wave 16x64 P
  __shared__ bf16 sVt[2048];     // 32x64 V^T (shared)
  const int tid = threadIdx.x;
  const int lane = tid & 63, wave = tid >> 6;
  const int win = blockIdx.x >> 4, h = blockIdx.x & 15;
  const size_t base = (size_t)win * 64;
  const int wi = win & 63, wh = wi >> 3, ww = wi & 7;

  // stage V transposed with XOR swizzle: Vt[d][k] at byte (d*128 + k*2) ^ ((d&7)<<4)
  {
    const int vrow = tid >> 2, cg = tid & 3;
    const bf16x8 v = *(const bf16x8*)(qkv + (base + vrow) * 1536 + 1024 + h * 32 + cg * 8);
#pragma unroll
    for (int j = 0; j < 8; j++) {
      const int d = cg * 8 + j;
      *(bf16*)((char*)sVt + ((d * 128 + vrow * 2) ^ ((d & 7) << 4))) = v[j];
    }
  }

  // Q strip (16 rows of this wave) + all K as B-operand fragments
  const bf16x8 qf = *(const bf16x8*)(qkv + (base + wave * 16 + (lane & 15)) * 1536 + h * 32 + (lane >> 4) * 8);
  bf16x8 kf[4];
#pragma unroll
  for (int ct = 0; ct < 4; ct++)
    kf[ct] = *(const bf16x8*)(qkv + (base + ct * 16 + (lane & 15)) * 1536 + 512 + h * 32 + (lane >> 4) * 8);

  const f32x4 fzero = {0.f, 0.f, 0.f, 0.f};
  f32x4 s[4];
#pragma unroll
  for (int ct = 0; ct < 4; ct++)
    s[ct] = __builtin_amdgcn_mfma_f32_16x16x32_bf16(qf, kf[ct], fzero, 0, 0, 0);

  char* Pw = (char*)sP[wave];
#pragma unroll
  for (int r = 0; r < 4; r++) {
    const int qloc = (lane >> 4) * 4 + r;
    const int t1 = wave * 16 + qloc;
    const int th1 = t1 >> 3, tw1 = t1 & 7;
    const int z1 = zone3(wh * 8 + th1) * 3 + zone3(ww * 8 + tw1);
    float z[4];
#pragma unroll
    for (int ct = 0; ct < 4; ct++) {
      const int t2 = ct * 16 + (lane & 15);
      const int th2 = t2 >> 3, tw2 = t2 & 7;
      const int z2 = zone3(wh * 8 + th2) * 3 + zone3(ww * 8 + tw2);
      const float bvv = rpb[((th1 - th2 + 7) * 15 + (tw1 - tw2 + 7)) * 16 + h];
      z[ct] = s[ct][r] * 0.17677669529663687f + bvv + (z1 != z2 ? -100.0f : 0.0f);
    }
    float mx = fmaxf(fmaxf(z[0], z[1]), fmaxf(z[2], z[3]));
#pragma unroll
    for (int msk = 1; msk < 16; msk <<= 1) mx = fmaxf(mx, __shfl_xor(mx, msk, 64));
    float p[4], sum = 0.f;
#pragma unroll
    for (int ct = 0; ct < 4; ct++) { p[ct] = __expf(z[ct] - mx); sum += p[ct]; }
#pragma unroll
    for (int msk = 1; msk < 16; msk <<= 1) sum += __shfl_xor(sum, msk, 64);
    const float inv = 1.0f / sum;
#pragma unroll
    for (int ct = 0; ct < 4; ct++) {
      const int t2 = ct * 16 + (lane & 15);
      *(bf16*)(Pw + ((qloc * 128 + t2 * 2) ^ ((qloc & 7) << 4))) = (bf16)(p[ct] * inv);
    }
  }

  __syncthreads();   // Vt ready (P is wave-private)

  f32x4 o[2] = {};
#pragma unroll
  for (int ks = 0; ks < 2; ks++) {
    const bf16x8 pa = *(const bf16x8*)(Pw +
        (((lane & 15) * 128 + ks * 64 + (lane >> 4) * 16) ^ (((lane & 15) & 7) << 4)));
#pragma unroll
    for (int dt = 0; dt < 2; dt++) {
      const int d = dt * 16 + (lane & 15);
      const bf16x8 vb = *(const bf16x8*)((char*)sVt +
          ((d * 128 + ks * 64 + (lane >> 4) * 16) ^ ((d & 7) << 4)));
      o[dt] = __builtin_amdgcn_mfma_f32_16x16x32_bf16(pa, vb, o[dt], 0, 0, 0);
    }
  }
#pragma unroll
  for (int dt = 0; dt < 2; dt++)
#pragma unroll
    for (int r = 0; r < 4; r++) {
      const size_t row = base + wave * 16 + (lane >> 4) * 4 + r;
      out[row * 512 + h * 32 + dt * 16 + (lane & 15)] = (bf16)o[dt][r];
    }
}

// ---------------------------------------------------------------------------
// Orchestration
// ---------------------------------------------------------------------------
extern "C" void kernel_launch(void* const* d_in, const int* in_sizes, int n_in,
                              void* d_out, int out_size, void* d_ws, size_t ws_size,
                              hipStream_t stream) {
  (void)in_sizes; (void)n_in; (void)out_size; (void)ws_size;
  const float* x      = (const float*)d_in[0];
  const float* n1g    = (const float*)d_in[1];
  const float* n1b    = (const float*)d_in[2];
  const float* qkv_w  = (const float*)d_in[3];
  const float* qkv_b  = (const float*)d_in[4];
  const float* proj_w = (const float*)d_in[5];
  const float* proj_b = (const float*)d_in[6];
  const float* rpb    = (const float*)d_in[7];
  const float* n2g    = (const float*)d_in[8];
  const float* n2b    = (const float*)d_in[9];
  const float* fc1_w  = (const float*)d_in[10];
  const float* fc1_b  = (const float*)d_in[11];
  const float* fc2_w  = (const float*)d_in[12];
  const float* fc2_b  = (const float*)d_in[13];
  float* out = (float*)d_out;

  // workspace layout (~926 MB):
  // [weights bf16 6MB][R1 128MB: A1/attn_out/A2][x1 f32 256MB][R2 536MB: qkv then H]
  char* ws = (char*)d_ws;
  bf16* wqkv  = (bf16*)ws;
  bf16* wproj = wqkv  + 1536 * 512;
  bf16* wfc1  = wproj + 512 * 512;
  bf16* wfc2  = wfc1  + 2048 * 512;
  size_t off = 2ull * (1536 * 512 + 512 * 512 + 2048 * 512 + 512 * 2048);
  bf16* R1 = (bf16*)(ws + off);  off += (size_t)131072 * 512 * 2;
  float* x1 = (float*)(ws + off); off += (size_t)131072 * 512 * 4;
  bf16* R2 = (bf16*)(ws + off);   // 131072*1536*2 (qkv) then reused as H (131072*2048*2)

  cast_w<<<768,  256, 0, stream>>>(qkv_w,  wqkv, 1536 * 512);
  cast_w<<<256,  256, 0, stream>>>(proj_w, wproj, 512 * 512);
  cast_w<<<1024, 256, 0, stream>>>(fc1_w,  wfc1, 2048 * 512);
  cast_w<<<1024, 256, 0, stream>>>(fc2_w,  wfc2, 512 * 2048);

  // LN1 + shift + window partition -> A1 (window order, bf16)
  ln_bf16<true><<<32768, 256, 0, stream>>>(x, n1g, n1b, R1);
  // QKV: [131072,512] x [1536,512]^T -> qkv bf16
  gemm_bt<M_QKV><<<12288, 256, 0, stream>>>(R1, wqkv, qkv_b, R2, nullptr, 1536, 512, 1536);
  // attention -> attn_out bf16 (reuses R1)
  attn_win<<<32768, 256, 0, stream>>>(R2, rpb, R1);
  // proj + window reverse + unshift + residual -> x1 f32
  gemm_bt<M_PROJ><<<4096, 256, 0, stream>>>(R1, wproj, proj_b, x1, x, 512, 512, 512);
  // LN2 -> A2 bf16 (reuses R1)
  ln_bf16<false><<<32768, 256, 0, stream>>>(x1, n2g, n2b, R1);
  // fc1 + GELU -> H bf16 (reuses R2, 512MB)
  gemm_bt<M_FC1><<<16384, 256, 0, stream>>>(R1, wfc1, fc1_b, R2, nullptr, 2048, 512, 2048);
  // fc2 + residual -> out f32
  gemm_bt<M_FC2><<<4096, 256, 0, stream>>>(R2, wfc2, fc2_b, out, x1, 512, 2048, 512);
}

// Round 3
// 2759.165 us; speedup vs baseline: 1.1000x; 1.1000x over previous
//
#include <hip/hip_runtime.h>
#include <cstdint>

typedef __bf16 bf16;
typedef bf16 bf16x8 __attribute__((ext_vector_type(8)));
typedef bf16 bf16x4 __attribute__((ext_vector_type(4)));
typedef float f32x4 __attribute__((ext_vector_type(4)));

#define DEVI __device__ __forceinline__

// Direct global->LDS (width 16). LDS dest is wave-uniform base; HW adds lane*16.
DEVI void gload_lds16(const void* g, void* l) {
  typedef __attribute__((address_space(1))) void gas_t;
  typedef __attribute__((address_space(3))) void las_t;
  __builtin_amdgcn_global_load_lds((gas_t*)g, (las_t*)l, 16, 0, 0);
}

// counted-vmcnt barrier: wait for all but N outstanding VMEM ops, then barrier.
#define WAITBAR(N) asm volatile("s_waitcnt vmcnt(" #N ")\n\ts_barrier" ::: "memory")
#define ENDBAR()   asm volatile("s_barrier" ::: "memory")
#define LGKMBAR()  asm volatile("s_waitcnt lgkmcnt(0)\n\ts_barrier" ::: "memory")

// ---------------------------------------------------------------------------
// Weight cast f32 -> bf16
// ---------------------------------------------------------------------------
__global__ void cast_w(const float* __restrict__ in, bf16* __restrict__ out, int n) {
  int i = (blockIdx.x * 256 + threadIdx.x) * 4;
  if (i >= n) return;
  f32x4 v = *(const f32x4*)(in + i);
  bf16x4 o;
#pragma unroll
  for (int j = 0; j < 4; j++) o[j] = (bf16)v[j];
  *(bf16x4*)(out + i) = o;
}

// ---------------------------------------------------------------------------
// LayerNorm (+ optional cyclic shift & window partition gather), f32 -> bf16
// ---------------------------------------------------------------------------
template<bool PERM>
__global__ __launch_bounds__(256, 4) void ln_bf16(
    const float* __restrict__ in, const float* __restrict__ gam,
    const float* __restrict__ bet, bf16* __restrict__ out)
{
  const int row = blockIdx.x * 4 + (threadIdx.x >> 6);
  const int lane = threadIdx.x & 63;
  size_t src;
  if constexpr (PERM) {
    const int rem = row & 4095, w = rem >> 6, t = rem & 63;
    const int r0 = ((w >> 3) * 8 + (t >> 3) + 4) & 63;
    const int c0 = ((w & 7) * 8 + (t & 7) + 4) & 63;
    src = ((size_t)(row >> 12) * 4096 + r0 * 64 + c0) * 512;
  } else {
    src = (size_t)row * 512;
  }
  const f32x4 v0 = *(const f32x4*)(in + src + lane * 8);
  const f32x4 v1 = *(const f32x4*)(in + src + lane * 8 + 4);
  float s  = v0[0] + v0[1] + v0[2] + v0[3] + v1[0] + v1[1] + v1[2] + v1[3];
  float sq = v0[0]*v0[0] + v0[1]*v0[1] + v0[2]*v0[2] + v0[3]*v0[3]
           + v1[0]*v1[0] + v1[1]*v1[1] + v1[2]*v1[2] + v1[3]*v1[3];
#pragma unroll
  for (int m = 1; m < 64; m <<= 1) { s += __shfl_xor(s, m, 64); sq += __shfl_xor(sq, m, 64); }
  const float mean = s * 0.001953125f;
  const float rstd = rsqrtf(sq * 0.001953125f - mean * mean + 1e-5f);
  const f32x4 g0 = *(const f32x4*)(gam + lane * 8), g1 = *(const f32x4*)(gam + lane * 8 + 4);
  const f32x4 b0 = *(const f32x4*)(bet + lane * 8), b1 = *(const f32x4*)(bet + lane * 8 + 4);
  bf16x8 o;
#pragma unroll
  for (int j = 0; j < 4; j++) o[j]     = (bf16)((v0[j] - mean) * rstd * g0[j] + b0[j]);
#pragma unroll
  for (int j = 0; j < 4; j++) o[4 + j] = (bf16)((v1[j] - mean) * rstd * g1[j] + b1[j]);
  *(bf16x8*)(out + (size_t)row * 512 + lane * 8) = o;
}

// ---------------------------------------------------------------------------
// bf16 GEMM: C[m,n] = sum_k A[m,k] * W[n,k]  (+ per-mode epilogue)
// 128x128 tile, BK=32, 4 waves (2x2), 16x16x32 MFMA.
// Ring-3 LDS pipeline with counted vmcnt (T4): stage tile t+2 while computing
// tile t; never a full vmcnt(0) drain in the main loop.
// Epilogue staged through LDS -> fully-coalesced row-major wide stores.
// ---------------------------------------------------------------------------
constexpr int M_QKV = 0, M_PROJ = 1, M_FC1 = 2, M_FC2 = 3;

template<int MODE>
__global__ __launch_bounds__(256, 2) void gemm_bt(
    const bf16* __restrict__ A, const bf16* __restrict__ W,
    const float* __restrict__ bias, void* __restrict__ Cout,
    const float* __restrict__ extra, int N, int K, int ldc)
{
  __shared__ char smem[49152] __attribute__((aligned(16)));   // 3 x (A 8KB + B 8KB)
  const int nN = N >> 7;
  const unsigned nwg = gridDim.x;
  const unsigned id = (blockIdx.x & 7) * (nwg >> 3) + (blockIdx.x >> 3);
  const int bn = id % nN;
  const int bm = id / nN;
  const int lane = threadIdx.x & 63;
  const int wave = threadIdx.x >> 6;
  const int wr = wave >> 1, wc = wave & 1;
  const size_t m0 = (size_t)bm * 128, n0 = (size_t)bn * 128;
  const int T = K >> 5;

  f32x4 acc[4][4] = {};

  // stage K-tile t into ring buffer buf: per wave 4 x gload_lds16 (2 A + 2 B)
  auto STAGE = [&](int t, int buf) {
    const int kb = t << 5;
    char* base = smem + buf * 16384;
#pragma unroll
    for (int cc = 0; cc < 2; cc++) {
      const int c = wave + cc * 4;
      const int u = c * 64 + lane;           // 16B unit: u = kg*128 + row (k-group-major)
      const int rr = u & 127, kg = u >> 7;
      gload_lds16(A + (m0 + rr) * K + kb + kg * 8, base + c * 1024);
      gload_lds16(W + (n0 + rr) * K + kb + kg * 8, base + 8192 + c * 1024);
    }
  };

  auto COMPUTE = [&](int buf) {
    const bf16* sAb = (const bf16*)(smem + buf * 16384);
    const bf16* sBb = sAb + 4096;
    bf16x8 af[4], bw[4];
#pragma unroll
    for (int i = 0; i < 4; i++) {
      af[i] = *(const bf16x8*)&sAb[(lane >> 4) * 1024 + (wr * 64 + i * 16 + (lane & 15)) * 8];
      bw[i] = *(const bf16x8*)&sBb[(lane >> 4) * 1024 + (wc * 64 + i * 16 + (lane & 15)) * 8];
    }
#pragma unroll
    for (int i = 0; i < 4; i++)
#pragma unroll
      for (int j = 0; j < 4; j++)
        acc[i][j] = __builtin_amdgcn_mfma_f32_16x16x32_bf16(af[i], bw[j], acc[i][j], 0, 0, 0);
  };

  STAGE(0, 0);
  STAGE(1, 1);
  int bs = 2, bc = 0;
  for (int t = 0; t < T - 2; ++t) {
    STAGE(t + 2, bs);
    WAITBAR(8);           // tile t's 4 loads (2 iters old) have landed
    COMPUTE(bc);
    ENDBAR();             // all waves done reading buf bc before it is restaged
    bs = bs + 1 < 3 ? bs + 1 : 0;
    bc = bc + 1 < 3 ? bc + 1 : 0;
  }
  WAITBAR(4);  COMPUTE(bc);  ENDBAR();
  bc = bc + 1 < 3 ? bc + 1 : 0;
  WAITBAR(0);  COMPUTE(bc);  ENDBAR();

  // ---- epilogue: acc -> LDS f32 (64x132 padded) -> coalesced wide stores ----
  float* sc = (float*)smem;
  const int lgrp = lane >> 4, lid = lane & 15;
#pragma unroll
  for (int h = 0; h < 2; ++h) {
    if (wr == h) {
#pragma unroll
      for (int i = 0; i < 4; i++)
#pragma unroll
        for (int j = 0; j < 4; j++)
#pragma unroll
          for (int r = 0; r < 4; r++)
            sc[(i * 16 + lgrp * 4 + r) * 132 + wc * 64 + j * 16 + lid] = acc[i][j][r];
    }
    LGKMBAR();
#pragma unroll
    for (int it = 0; it < 8; it++) {
      const int ch = threadIdx.x + it * 256;       // 2048 chunks of 4 cols
      const int lr = ch >> 5, c4 = (ch & 31) * 4;
      f32x4 v = *(const f32x4*)&sc[lr * 132 + c4];
      const int gm = (int)m0 + h * 64 + lr;
      const int gn = (int)n0 + c4;
      const f32x4 bv = *(const f32x4*)(bias + gn);
      if constexpr (MODE == M_QKV) {
        bf16x4 o;
#pragma unroll
        for (int j = 0; j < 4; j++) o[j] = (bf16)(v[j] + bv[j]);
        *(bf16x4*)((bf16*)Cout + (size_t)gm * ldc + gn) = o;
      } else if constexpr (MODE == M_FC1) {
        bf16x4 o;
#pragma unroll
        for (int j = 0; j < 4; j++) {
          const float z = v[j] + bv[j];
          o[j] = (bf16)(0.5f * z * (1.0f + erff(z * 0.70710678118f)));
        }
        *(bf16x4*)((bf16*)Cout + (size_t)gm * ldc + gn) = o;
      } else if constexpr (MODE == M_PROJ) {
        // window reverse + unshift + residual (rows permute; cols contiguous)
        const int rem = gm & 4095, w = rem >> 6, t = rem & 63;
        const int r0 = ((w >> 3) * 8 + (t >> 3) + 4) & 63;
        const int c0 = ((w & 7) * 8 + (t & 7) + 4) & 63;
        const size_t idx = ((size_t)(gm >> 12) * 4096 + r0 * 64 + c0) * 512 + gn;
        const f32x4 e = *(const f32x4*)(extra + idx);
        f32x4 o;
#pragma unroll
        for (int j = 0; j < 4; j++) o[j] = e[j] + v[j] + bv[j];
        *(f32x4*)((float*)Cout + idx) = o;
      } else {  // M_FC2
        const size_t idx = (size_t)gm * 512 + gn;
        const f32x4 e = *(const f32x4*)(extra + idx);
        f32x4 o;
#pragma unroll
        for (int j = 0; j < 4; j++) o[j] = e[j] + v[j] + bv[j];
        *(f32x4*)((float*)Cout + idx) = o;
      }
    }
    if (h == 0) ENDBAR();   // sc reused by second half-tile pass
  }
}

// ---------------------------------------------------------------------------
// Windowed attention: one block per (window, head). 4 waves split the 64 q-rows.
// ---------------------------------------------------------------------------
DEVI int zone3(int r) { return r < 56 ? 0 : (r < 60 ? 1 : 2); }

__global__ __launch_bounds__(256, 2) void attn_win(
    const bf16* __restrict__ qkv, const float* __restrict__ rpb, bf16* __restrict__ out)
{
  __shared__ bf16 sP[4][1024];   // per-wave 16x64 P
  __shared__ bf16 sVt[2048];     // 32x64 V^T (shared)
  const int tid = threadIdx.x;
  const int lane = tid & 63, wave = tid >> 6;
  const int win = blockIdx.x >> 4, h = blockIdx.x & 15;
  const size_t base = (size_t)win * 64;
  const int wi = win & 63, wh = wi >> 3, ww = wi & 7;

  {
    const int vrow = tid >> 2, cg = tid & 3;
    const bf16x8 v = *(const bf16x8*)(qkv + (base + vrow) * 1536 + 1024 + h * 32 + cg * 8);
#pragma unroll
    for (int j = 0; j < 8; j++) {
      const int d = cg * 8 + j;
      *(bf16*)((char*)sVt + ((d * 128 + vrow * 2) ^ ((d & 7) << 4))) = v[j];
    }
  }

  const bf16x8 qf = *(const bf16x8*)(qkv + (base + wave * 16 + (lane & 15)) * 1536 + h * 32 + (lane >> 4) * 8);
  bf16x8 kf[4];
#pragma unroll
  for (int ct = 0; ct < 4; ct++)
    kf[ct] = *(const bf16x8*)(qkv + (base + ct * 16 + (lane & 15)) * 1536 + 512 + h * 32 + (lane >> 4) * 8);

  const f32x4 fzero = {0.f, 0.f, 0.f, 0.f};
  f32x4 s[4];
#pragma unroll
  for (int ct = 0; ct < 4; ct++)
    s[ct] = __builtin_amdgcn_mfma_f32_16x16x32_bf16(qf, kf[ct], fzero, 0, 0, 0);

  char* Pw = (char*)sP[wave];
#pragma unroll
  for (int r = 0; r < 4; r++) {
    const int qloc = (lane >> 4) * 4 + r;
    const int t1 = wave * 16 + qloc;
    const int th1 = t1 >> 3, tw1 = t1 & 7;
    const int z1 = zone3(wh * 8 + th1) * 3 + zone3(ww * 8 + tw1);
    float z[4];
#pragma unroll
    for (int ct = 0; ct < 4; ct++) {
      const int t2 = ct * 16 + (lane & 15);
      const int th2 = t2 >> 3, tw2 = t2 & 7;
      const int z2 = zone3(wh * 8 + th2) * 3 + zone3(ww * 8 + tw2);
      const float bvv = rpb[((th1 - th2 + 7) * 15 + (tw1 - tw2 + 7)) * 16 + h];
      z[ct] = s[ct][r] * 0.17677669529663687f + bvv + (z1 != z2 ? -100.0f : 0.0f);
    }
    float mx = fmaxf(fmaxf(z[0], z[1]), fmaxf(z[2], z[3]));
#pragma unroll
    for (int msk = 1; msk < 16; msk <<= 1) mx = fmaxf(mx, __shfl_xor(mx, msk, 64));
    float p[4], sum = 0.f;
#pragma unroll
    for (int ct = 0; ct < 4; ct++) { p[ct] = __expf(z[ct] - mx); sum += p[ct]; }
#pragma unroll
    for (int msk = 1; msk < 16; msk <<= 1) sum += __shfl_xor(sum, msk, 64);
    const float inv = 1.0f / sum;
#pragma unroll
    for (int ct = 0; ct < 4; ct++) {
      const int t2 = ct * 16 + (lane & 15);
      *(bf16*)(Pw + ((qloc * 128 + t2 * 2) ^ ((qloc & 7) << 4))) = (bf16)(p[ct] * inv);
    }
  }

  __syncthreads();   // Vt ready (P is wave-private)

  f32x4 o[2] = {};
#pragma unroll
  for (int ks = 0; ks < 2; ks++) {
    const bf16x8 pa = *(const bf16x8*)(Pw +
        (((lane & 15) * 128 + ks * 64 + (lane >> 4) * 16) ^ (((lane & 15) & 7) << 4)));
#pragma unroll
    for (int dt = 0; dt < 2; dt++) {
      const int d = dt * 16 + (lane & 15);
      const bf16x8 vb = *(const bf16x8*)((char*)sVt +
          ((d * 128 + ks * 64 + (lane >> 4) * 16) ^ ((d & 7) << 4)));
      o[dt] = __builtin_amdgcn_mfma_f32_16x16x32_bf16(pa, vb, o[dt], 0, 0, 0);
    }
  }
#pragma unroll
  for (int dt = 0; dt < 2; dt++)
#pragma unroll
    for (int r = 0; r < 4; r++) {
      const size_t row = base + wave * 16 + (lane >> 4) * 4 + r;
      out[row * 512 + h * 32 + dt * 16 + (lane & 15)] = (bf16)o[dt][r];
    }
}

// ---------------------------------------------------------------------------
// Orchestration
// ---------------------------------------------------------------------------
extern "C" void kernel_launch(void* const* d_in, const int* in_sizes, int n_in,
                              void* d_out, int out_size, void* d_ws, size_t ws_size,
                              hipStream_t stream) {
  (void)in_sizes; (void)n_in; (void)out_size; (void)ws_size;
  const float* x      = (const float*)d_in[0];
  const float* n1g    = (const float*)d_in[1];
  const float* n1b    = (const float*)d_in[2];
  const float* qkv_w  = (const float*)d_in[3];
  const float* qkv_b  = (const float*)d_in[4];
  const float* proj_w = (const float*)d_in[5];
  const float* proj_b = (const float*)d_in[6];
  const float* rpb    = (const float*)d_in[7];
  const float* n2g    = (const float*)d_in[8];
  const float* n2b    = (const float*)d_in[9];
  const float* fc1_w  = (const float*)d_in[10];
  const float* fc1_b  = (const float*)d_in[11];
  const float* fc2_w  = (const float*)d_in[12];
  const float* fc2_b  = (const float*)d_in[13];
  float* out = (float*)d_out;

  char* ws = (char*)d_ws;
  bf16* wqkv  = (bf16*)ws;
  bf16* wproj = wqkv  + 1536 * 512;
  bf16* wfc1  = wproj + 512 * 512;
  bf16* wfc2  = wfc1  + 2048 * 512;
  size_t off = 2ull * (1536 * 512 + 512 * 512 + 2048 * 512 + 512 * 2048);
  bf16* R1 = (bf16*)(ws + off);  off += (size_t)131072 * 512 * 2;
  float* x1 = (float*)(ws + off); off += (size_t)131072 * 512 * 4;
  bf16* R2 = (bf16*)(ws + off);   // qkv [131072,1536] bf16, then reused as H [131072,2048]

  cast_w<<<768,  256, 0, stream>>>(qkv_w,  wqkv, 1536 * 512);
  cast_w<<<256,  256, 0, stream>>>(proj_w, wproj, 512 * 512);
  cast_w<<<1024, 256, 0, stream>>>(fc1_w,  wfc1, 2048 * 512);
  cast_w<<<1024, 256, 0, stream>>>(fc2_w,  wfc2, 512 * 2048);

  ln_bf16<true><<<32768, 256, 0, stream>>>(x, n1g, n1b, R1);
  gemm_bt<M_QKV><<<12288, 256, 0, stream>>>(R1, wqkv, qkv_b, R2, nullptr, 1536, 512, 1536);
  attn_win<<<32768, 256, 0, stream>>>(R2, rpb, R1);
  gemm_bt<M_PROJ><<<4096, 256, 0, stream>>>(R1, wproj, proj_b, x1, x, 512, 512, 512);
  ln_bf16<false><<<32768, 256, 0, stream>>>(x1, n2g, n2b, R1);
  gemm_bt<M_FC1><<<16384, 256, 0, stream>>>(R1, wfc1, fc1_b, R2, nullptr, 2048, 512, 2048);
  gemm_bt<M_FC2><<<4096, 256, 0, stream>>>(R2, wfc2, fc2_b, out, x1, 512, 2048, 512);
}